// Round 3
// baseline (560.290 us; speedup 1.0000x reference)
//
#include <hip/hip_runtime.h>
#include <hip/hip_bf16.h>
#include <stdint.h>

#define S_LEN   2048
#define DIN     2048
#define NHEADS  32
#define HDIM    64
#define NKV     8

typedef __bf16 bf16x8 __attribute__((ext_vector_type(8)));
typedef float  f32x4  __attribute__((ext_vector_type(4)));

#define AS1(p) ((__attribute__((address_space(1))) void*)(void*)(p))
#define AS3(p) ((__attribute__((address_space(3))) void*)(p))
#define MFMA_BF16 __builtin_amdgcn_mfma_f32_16x16x32_bf16

#if __has_builtin(__builtin_amdgcn_exp2f)
#define EXP2F(x) __builtin_amdgcn_exp2f(x)
#else
#define EXP2F(x) exp2f(x)
#endif

static __device__ __forceinline__ unsigned short f2bf(float f) {
  unsigned int x = __float_as_uint(f);
  return (unsigned short)((x + 0x7fffu + ((x >> 16) & 1u)) >> 16);
}
static __device__ __forceinline__ float bf2f(unsigned short u) {
  return __uint_as_float((unsigned int)u << 16);
}

// ---------------- cast x (fp32 -> bf16), vectorized ----------------
__global__ __launch_bounds__(256) void cast_x_kernel(const float* __restrict__ x,
                                                     unsigned short* __restrict__ xb, int n4) {
  int i = blockIdx.x * 256 + threadIdx.x;
  if (i >= n4) return;
  float4 f = ((const float4*)x)[i];
  ushort4 o = make_ushort4(f2bf(f.x), f2bf(f.y), f2bf(f.z), f2bf(f.w));
  ((ushort4*)xb)[i] = o;
}

// ---------------- transpose + cast: src fp32 [K][N] -> dst bf16 [N][K] ----------------
__global__ __launch_bounds__(256) void transpose_cast(const float* __restrict__ src,
                                                      unsigned short* __restrict__ dst,
                                                      int K, int N) {
  __shared__ float t[32][33];
  int n0 = blockIdx.x * 32, k0 = blockIdx.y * 32;
  int x = threadIdx.x, y = threadIdx.y;
  #pragma unroll
  for (int j = 0; j < 32; j += 8)
    t[y + j][x] = src[(size_t)(k0 + y + j) * N + n0 + x];
  __syncthreads();
  #pragma unroll
  for (int j = 0; j < 32; j += 8)
    dst[(size_t)(n0 + y + j) * K + k0 + x] = f2bf(t[x][y + j]);
}

// ---------------- fused W transpose: [Wq|Wk|Wv] -> wcat bf16 [3072][2048] ----------------
__global__ __launch_bounds__(256) void transpose_cast_wqkv(const float* __restrict__ Wq,
                                                           const float* __restrict__ Wk,
                                                           const float* __restrict__ Wv,
                                                           unsigned short* __restrict__ dst) {
  __shared__ float t[32][33];
  int n0 = blockIdx.x * 32, k0 = blockIdx.y * 32;   // n0 in [0,3072)
  const float* src; int col0, srcN;
  if (n0 < 2048)      { src = Wq; col0 = n0;        srcN = 2048; }
  else if (n0 < 2560) { src = Wk; col0 = n0 - 2048; srcN = 512; }
  else                { src = Wv; col0 = n0 - 2560; srcN = 512; }
  int x = threadIdx.x, y = threadIdx.y;
  #pragma unroll
  for (int j = 0; j < 32; j += 8)
    t[y + j][x] = src[(size_t)(k0 + y + j) * srcN + col0 + x];
  __syncthreads();
  #pragma unroll
  for (int j = 0; j < 32; j += 8)
    dst[(size_t)(n0 + y + j) * 2048 + k0 + x] = f2bf(t[x][y + j]);
}

// ---------------- bf16 NT GEMM: C[M][N] = A[M][K] * Bt[N][K]^T (fp32 or bf16 out) ----
// m97 structure + XOR-swizzled LDS (swizzle realized via per-lane global address
// permutation in global_load_lds; consumer reads land 2-way/bank = free).
template <typename OutT>
__global__ __launch_bounds__(256) void gemm_nt(const unsigned short* __restrict__ A,
                                               const unsigned short* __restrict__ Bt,
                                               OutT* __restrict__ C,
                                               int M, int N, int K) {
  __shared__ alignas(16) unsigned short As[128 * 32];
  __shared__ alignas(16) unsigned short Bs[128 * 32];
  const int tid = threadIdx.x;
  const int wave = tid >> 6, lane = tid & 63;
  const int g = lane >> 4, c = lane & 15;
  const int m0 = blockIdx.y * 128, n0 = blockIdx.x * 128;
  const int wm = (wave & 1) * 64, wn = (wave >> 1) * 64;

  f32x4 acc[4][4] = {};

  const int ch0 = wave * 2;
  const int p0 = ch0 * 64 + lane, p1 = p0 + 64;
  const int r0 = p0 >> 2, gc0 = ((p0 & 3) ^ ((r0 >> 1) & 3)) * 8;
  const int r1 = p1 >> 2, gc1 = ((p1 & 3) ^ ((r1 >> 1) & 3)) * 8;
  const unsigned short* a0 = A + (size_t)(m0 + r0) * K + gc0;
  const unsigned short* a1 = A + (size_t)(m0 + r1) * K + gc1;
  const unsigned short* b0 = Bt + (size_t)(n0 + r0) * K + gc0;
  const unsigned short* b1 = Bt + (size_t)(n0 + r1) * K + gc1;
  const int fswz = (c >> 1) & 3;   // f(row) for consumer rows (wm,i*16 are mult of 16)

  for (int k0 = 0; k0 < K; k0 += 32) {
    __syncthreads();
    __builtin_amdgcn_global_load_lds(AS1(a0 + k0), AS3(As + ch0 * 512), 16, 0, 0);
    __builtin_amdgcn_global_load_lds(AS1(a1 + k0), AS3(As + ch0 * 512 + 512), 16, 0, 0);
    __builtin_amdgcn_global_load_lds(AS1(b0 + k0), AS3(Bs + ch0 * 512), 16, 0, 0);
    __builtin_amdgcn_global_load_lds(AS1(b1 + k0), AS3(Bs + ch0 * 512 + 512), 16, 0, 0);
    __builtin_amdgcn_s_waitcnt(0);
    __syncthreads();

    bf16x8 af[4], bfr[4];
    #pragma unroll
    for (int i = 0; i < 4; i++)
      af[i] = *(const bf16x8*)(As + (wm + i * 16 + c) * 32 + (g ^ fswz) * 8);
    #pragma unroll
    for (int j = 0; j < 4; j++)
      bfr[j] = *(const bf16x8*)(Bs + (wn + j * 16 + c) * 32 + (g ^ fswz) * 8);
    #pragma unroll
    for (int i = 0; i < 4; i++)
      #pragma unroll
      for (int j = 0; j < 4; j++)
        acc[i][j] = MFMA_BF16(af[i], bfr[j], acc[i][j], 0, 0, 0);
  }

  #pragma unroll
  for (int i = 0; i < 4; i++)
    #pragma unroll
    for (int j = 0; j < 4; j++)
      #pragma unroll
      for (int r = 0; r < 4; r++) {
        size_t idx = (size_t)(m0 + wm + i * 16 + g * 4 + r) * N + n0 + wn + j * 16 + c;
        if constexpr (sizeof(OutT) == 2) C[idx] = f2bf(acc[i][j][r]);
        else                             C[idx] = acc[i][j][r];
      }
}

// ---------------- RMSNorm + RoPE for Q and K heads (bf16 QKV input) ----------------
// SC = log2(e)/sqrt(64) folded into Q here (attention uses exp2 with fixed max 0).
// 4 tasks per wave to amortize wave launch overhead.
__global__ __launch_bounds__(256) void norm_rope(const unsigned short* __restrict__ QKV,
                                                 const float* __restrict__ cosb,
                                                 const float* __restrict__ sinb,
                                                 const float* __restrict__ q_scale,
                                                 const float* __restrict__ k_scale,
                                                 unsigned short* __restrict__ Qn,
                                                 unsigned short* __restrict__ Kn) {
  const int tid = threadIdx.x, w = tid >> 6, d = tid & 63;
  const float qs = q_scale[d], ks = k_scale[d];
  #pragma unroll
  for (int k = 0; k < 4; k++) {
    int task = blockIdx.x * 16 + w * 4 + k;
    const int hid = task % 40;
    const int row = task / 40;            // b*2048 + s
    const int b = row >> 11, s = row & 2047;
    float val, sc;
    if (hid < 32) {
      val = bf2f(QKV[(size_t)row * 3072 + hid * 64 + d]);
      sc = qs;
    } else {
      val = bf2f(QKV[(size_t)row * 3072 + 2048 + (hid - 32) * 64 + d]);
      sc = ks;
    }
    float v2 = val * val;
    #pragma unroll
    for (int off = 32; off; off >>= 1) v2 += __shfl_xor(v2, off);
    float t = val * (1.0f / sqrtf(v2 * (1.0f / 64.0f) + 1e-6f)) * sc;
    float partner = __shfl_xor(t, 32);
    float rot = (d < 32) ? -partner : partner;
    float o = t * cosb[s * 64 + d] + rot * sinb[s * 64 + d];
    if (hid < 32) o *= 0.18033688011112042f;   // fold softmax scale into Q
    unsigned short ob = f2bf(o);
    if (hid < 32) Qn[((size_t)(b * 32 + hid) * 2048 + s) * 64 + d] = ob;
    else          Kn[((size_t)(b * 8 + (hid - 32)) * 2048 + s) * 64 + d] = ob;
  }
}

// ---------------- V transpose: bf16 QKV V-cols -> Vt bf16 [b][kv][D][S] ----------------
__global__ __launch_bounds__(256) void v_transpose(const unsigned short* __restrict__ QKV,
                                                   unsigned short* __restrict__ Vt) {
  __shared__ unsigned int t[64][65];
  int bid = blockIdx.x;
  const int st = bid & 31, kv = (bid >> 5) & 7, b = bid >> 8;
  const int tid = threadIdx.x, lane = tid & 63, quad = tid >> 6;
  #pragma unroll
  for (int p = 0; p < 16; p++) {
    int sl = p * 4 + quad;
    t[sl][lane] = QKV[(size_t)(b * 2048 + st * 64 + sl) * 3072 + 2560 + kv * 64 + lane];
  }
  __syncthreads();
  size_t base = (size_t)(b * 8 + kv) * 64 * 2048;
  #pragma unroll
  for (int p = 0; p < 16; p++) {
    int dd = p * 4 + quad;
    Vt[base + (size_t)dd * 2048 + st * 64 + lane] = (unsigned short)t[lane][dd];
  }
}

// ---------------- causal flash attention v8 ----------------
// Bisection of v7's correctness failure: KEEP the occupancy restructure
// (jb-split QK/softmax with Sx live=16, av/av2 split, bp t-split, K prefetch
// at PV-t0, int offsets, launch_bounds(256,4)); REVERT the two numeric-path
// changes to v6-verified forms (manual +0x8000/v_perm bf16 pack; VALU lv
// row-sum + shfl_xor butterfly). If this passes, the restructure is validated
// and cvt_pk / MFMA-rowsum get A/B'd individually next.
__global__ __launch_bounds__(256, 4) void attn_kernel(const unsigned short* __restrict__ Qn,
                                                      const unsigned short* __restrict__ Kn,
                                                      const unsigned short* __restrict__ Vt,
                                                      unsigned short* __restrict__ Outv) {
  __shared__ alignas(16) char smem[4 * 4352];

  const int tid = threadIdx.x, w = tid >> 6, lane = tid & 63;
  const int g = lane >> 4, c = lane & 15;
  const int bid = blockIdx.x;                      // [0, 1024)
  const int qt = 63 - (bid >> 4);                  // longest blocks first
  const int rem = bid & 15;
  const int hg = rem & 7, b = rem >> 3;
  const int h = hg * 4 + w;
  const int kvh = hg;
  const int Q0 = qt * 32;
  const unsigned short* Qp = Qn + ((size_t)(b * NHEADS + h) * S_LEN + Q0) * HDIM;
  const unsigned short* Kp = Kn + (size_t)(b * NKV + kvh) * S_LEN * HDIM;
  const unsigned short* Vp = Vt + (size_t)(b * NKV + kvh) * HDIM * S_LEN;  // [d][s]
  const int ntiles = (qt >> 1) + 1;
  char* PwB = smem + w * 4352;   // this wave's P buffer (32 rows x 128 B, swizzled)

  // Q as B-operand: B[k=d][n=q], n = c, k = g*8+j (+t*32)
  bf16x8 bq[2][2];
  #pragma unroll
  for (int iq = 0; iq < 2; iq++)
    #pragma unroll
    for (int t = 0; t < 2; t++)
      bq[iq][t] = *(const bf16x8*)(Qp + (iq * 16 + c) * HDIM + t * 32 + g * 8);

  f32x4 OT[4][2] = {};          // O^T tiles: [dt][iq], row=d, col=q
  f32x4 lv[2] = {};             // per-lane l partials

  bf16x8 ak[4][2];              // current K tile (A-operand: A[m=kv][k=d])
  #pragma unroll
  for (int jt = 0; jt < 4; jt++)
    #pragma unroll
    for (int t = 0; t < 2; t++)
      ak[jt][t] = *(const bf16x8*)(Kp + (jt * 16 + c) * HDIM + t * 32 + g * 8);

  for (int ti = 0; ti < ntiles; ti++) {
    const int kv0 = ti * 64;

    // V half-tile t=0 (A-operand: A[m=d][k=kv]) — consumed at PV-t0
    bf16x8 av[4];
    #pragma unroll
    for (int dt = 0; dt < 4; dt++)
      av[dt] = *(const bf16x8*)(Vp + (dt * 16 + c) * S_LEN + kv0 + g * 8);

    // QK + softmax in two jt-pairs (Sx live = 16 regs)
    #pragma unroll
    for (int jb = 0; jb < 2; jb++) {
      f32x4 Sx[2][2] = {};
      #pragma unroll
      for (int t = 0; t < 2; t++)
        #pragma unroll
        for (int jt = 0; jt < 2; jt++)
          #pragma unroll
          for (int iq = 0; iq < 2; iq++)
            Sx[jt][iq] = MFMA_BF16(ak[jb * 2 + jt][t], bq[iq][t], Sx[jt][iq], 0, 0, 0);

      if (ti == ntiles - 1) {   // only the final tile crosses the diagonal
        #pragma unroll
        for (int jt = 0; jt < 2; jt++)
          #pragma unroll
          for (int iq = 0; iq < 2; iq++)
            #pragma unroll
            for (int r = 0; r < 4; r++) {
              int kv = kv0 + (jb * 2 + jt) * 16 + g * 4 + r;
              int q  = Q0 + iq * 16 + c;
              if (kv > q) Sx[jt][iq][r] = -1e30f;
            }
      }

      // fixed-max softmax: p = exp2(s); accumulate l; pack P -> LDS (swizzled)
      #pragma unroll
      for (int jt = 0; jt < 2; jt++)
        #pragma unroll
        for (int iq = 0; iq < 2; iq++) {
          f32x4 p;
          #pragma unroll
          for (int r = 0; r < 4; r++) p[r] = EXP2F(Sx[jt][iq][r]);
          lv[iq] += p;
          uint32_t u0 = __float_as_uint(p[0]) + 0x8000u;
          uint32_t u1 = __float_as_uint(p[1]) + 0x8000u;
          uint32_t u2 = __float_as_uint(p[2]) + 0x8000u;
          uint32_t u3 = __float_as_uint(p[3]) + 0x8000u;
          uint32_t lo = __builtin_amdgcn_perm(u1, u0, 0x07060302u);
          uint32_t hi = __builtin_amdgcn_perm(u3, u2, 0x07060302u);
          int row = iq * 16 + c;                       // local q
          int bytecol = (jb * 2 + jt) * 32 + g * 8;    // kv-contiguous bytes
          uint32_t off = row * 128 + (((bytecol >> 4) ^ (row & 7)) << 4) + (bytecol & 15);
          *(uint2*)(PwB + off) = make_uint2(lo, hi);
        }
    }

    // V half-tile t=1 — issued before the lgkm wait; latency hides under bp0+PV-t0
    bf16x8 av2[4];
    #pragma unroll
    for (int dt = 0; dt < 4; dt++)
      av2[dt] = *(const bf16x8*)(Vp + (dt * 16 + c) * S_LEN + kv0 + 32 + g * 8);

    __builtin_amdgcn_s_waitcnt(0xC07F);        // lgkmcnt(0) only — keep VMEM in flight

    // PV per t-half: P as B-operand B[k=kv][n=q]; bp live = 8 regs
    #pragma unroll
    for (int t = 0; t < 2; t++) {
      bf16x8 bpt[2];
      #pragma unroll
      for (int iq = 0; iq < 2; iq++) {
        int row = iq * 16 + c;
        int bytecol = t * 64 + g * 16;
        uint32_t off = row * 128 + (((bytecol >> 4) ^ (row & 7)) << 4);
        bpt[iq] = *(const bf16x8*)(PwB + off);
      }
      #pragma unroll
      for (int dt = 0; dt < 4; dt++)
        #pragma unroll
        for (int iq = 0; iq < 2; iq++)
          OT[dt][iq] = MFMA_BF16(t ? av2[dt] : av[dt], bpt[iq], OT[dt][iq], 0, 0, 0);

      // in-place K prefetch for next tile (ak dead since pair-1 QK issued)
      if (t == 0 && ti + 1 < ntiles) {
        const int kvn = kv0 + 64;
        #pragma unroll
        for (int jt = 0; jt < 4; jt++)
          #pragma unroll
          for (int tt = 0; tt < 2; tt++)
            ak[jt][tt] = *(const bf16x8*)(Kp + (kvn + jt * 16 + c) * HDIM + tt * 32 + g * 8);
      }
    }
  }

  // l: sum lane partials (kv mod 16 split across g) -> butterfly over g
  float inv[2];
  #pragma unroll
  for (int iq = 0; iq < 2; iq++) {
    float s = lv[iq][0] + lv[iq][1] + lv[iq][2] + lv[iq][3];
    s += __shfl_xor(s, 16);
    s += __shfl_xor(s, 32);
    inv[iq] = 1.0f / s;
  }

  // write O: lane holds d = dt*16+g*4+{0..3}, q = Q0+iq*16+c -> 8B stores
  #pragma unroll
  for (int iq = 0; iq < 2; iq++) {
    const int q = Q0 + iq * 16 + c;
    unsigned short* orow = Outv + (size_t)(b * S_LEN + q) * (NHEADS * HDIM) + h * HDIM;
    #pragma unroll
    for (int dt = 0; dt < 4; dt++) {
      uint32_t u0 = __float_as_uint(OT[dt][iq][0] * inv[iq]) + 0x8000u;
      uint32_t u1 = __float_as_uint(OT[dt][iq][1] * inv[iq]) + 0x8000u;
      uint32_t u2 = __float_as_uint(OT[dt][iq][2] * inv[iq]) + 0x8000u;
      uint32_t u3 = __float_as_uint(OT[dt][iq][3] * inv[iq]) + 0x8000u;
      uint32_t lo = __builtin_amdgcn_perm(u1, u0, 0x07060302u);
      uint32_t hi = __builtin_amdgcn_perm(u3, u2, 0x07060302u);
      *(uint2*)(orow + dt * 16 + g * 4) = make_uint2(lo, hi);
    }
  }
}

extern "C" void kernel_launch(void* const* d_in, const int* in_sizes, int n_in,
                              void* d_out, int out_size, void* d_ws, size_t ws_size,
                              hipStream_t stream) {
  const float* x       = (const float*)d_in[0];
  // d_in[1] = mask (causal, implemented analytically)
  const float* cosb    = (const float*)d_in[2];
  const float* sinb    = (const float*)d_in[3];
  const float* Wq      = (const float*)d_in[4];
  const float* Wk      = (const float*)d_in[5];
  const float* Wv      = (const float*)d_in[6];
  const float* Wo      = (const float*)d_in[7];
  const float* q_scale = (const float*)d_in[8];
  const float* k_scale = (const float*)d_in[9];

  char* ws = (char*)d_ws;
  unsigned short* xb   = (unsigned short*)(ws);                       // 16 MiB: x bf16 [4096][2048]
  unsigned short* wcat = (unsigned short*)(ws + (16ull << 20));       // 12 MiB: Wt [3072][2048]
  unsigned short* wo_t = (unsigned short*)(ws + (28ull << 20));       //  8 MiB: Wo_t [2048][2048]
  unsigned short* qkv  = (unsigned short*)(ws + (36ull << 20));       // 24 MiB: QKV bf16 [4096][3072]
  unsigned short* qn   = (unsigned short*)(ws + (84ull << 20));       // 16 MiB: Q bf16 [b][h][s][d]
  unsigned short* kn   = (unsigned short*)(ws + (100ull << 20));      //  4 MiB: K bf16 [b][kv][s][d]
  unsigned short* vt   = (unsigned short*)(ws + (104ull << 20));      //  4 MiB: V^T bf16 [b][kv][d][s]
  unsigned short* vec  = (unsigned short*)(ws + (36ull << 20));       // alias qkv (dead after v_transpose)

  cast_x_kernel<<<8192, 256, 0, stream>>>(x, xb, 2097152);
  dim3 tb(32, 8);
  transpose_cast_wqkv<<<dim3(96, 64), tb, 0, stream>>>(Wq, Wk, Wv, wcat);
  transpose_cast<<<dim3(64, 64), tb, 0, stream>>>(Wo, wo_t, 2048, 2048);

  gemm_nt<unsigned short><<<dim3(24, 32), 256, 0, stream>>>(xb, wcat, qkv, 4096, 3072, 2048);
  norm_rope<<<10240, 256, 0, stream>>>(qkv, cosb, sinb, q_scale, k_scale, qn, kn);
  v_transpose<<<512, 256, 0, stream>>>(qkv, vt);
  attn_kernel<<<1024, 256, 0, stream>>>(qn, kn, vt, vec);
  gemm_nt<float><<<dim3(16, 32), 256, 0, stream>>>(vec, wo_t, (float*)d_out, 4096, 2048, 2048);
}

// Round 4
// 432.153 us; speedup vs baseline: 1.2965x; 1.2965x over previous
//
#include <hip/hip_runtime.h>
#include <hip/hip_bf16.h>
#include <stdint.h>

#define S_LEN   2048
#define DIN     2048
#define NHEADS  32
#define HDIM    64
#define NKV     8

typedef __bf16 bf16x8 __attribute__((ext_vector_type(8)));
typedef float  f32x4  __attribute__((ext_vector_type(4)));

#define AS1(p) ((__attribute__((address_space(1))) void*)(void*)(p))
#define AS3(p) ((__attribute__((address_space(3))) void*)(p))
#define MFMA_BF16 __builtin_amdgcn_mfma_f32_16x16x32_bf16

#if __has_builtin(__builtin_amdgcn_exp2f)
#define EXP2F(x) __builtin_amdgcn_exp2f(x)
#else
#define EXP2F(x) exp2f(x)
#endif

static __device__ __forceinline__ unsigned short f2bf(float f) {
  unsigned int x = __float_as_uint(f);
  return (unsigned short)((x + 0x7fffu + ((x >> 16) & 1u)) >> 16);
}
static __device__ __forceinline__ float bf2f(unsigned short u) {
  return __uint_as_float((unsigned int)u << 16);
}

// ---------------- cast x (fp32 -> bf16), vectorized ----------------
__global__ __launch_bounds__(256) void cast_x_kernel(const float* __restrict__ x,
                                                     unsigned short* __restrict__ xb, int n4) {
  int i = blockIdx.x * 256 + threadIdx.x;
  if (i >= n4) return;
  float4 f = ((const float4*)x)[i];
  ushort4 o = make_ushort4(f2bf(f.x), f2bf(f.y), f2bf(f.z), f2bf(f.w));
  ((ushort4*)xb)[i] = o;
}

// ---------------- transpose + cast: src fp32 [K][N] -> dst bf16 [N][K] ----------------
__global__ __launch_bounds__(256) void transpose_cast(const float* __restrict__ src,
                                                      unsigned short* __restrict__ dst,
                                                      int K, int N) {
  __shared__ float t[32][33];
  int n0 = blockIdx.x * 32, k0 = blockIdx.y * 32;
  int x = threadIdx.x, y = threadIdx.y;
  #pragma unroll
  for (int j = 0; j < 32; j += 8)
    t[y + j][x] = src[(size_t)(k0 + y + j) * N + n0 + x];
  __syncthreads();
  #pragma unroll
  for (int j = 0; j < 32; j += 8)
    dst[(size_t)(n0 + y + j) * K + k0 + x] = f2bf(t[x][y + j]);
}

// ---------------- fused W transpose: [Wq|Wk|Wv] -> wcat bf16 [3072][2048] ----------------
__global__ __launch_bounds__(256) void transpose_cast_wqkv(const float* __restrict__ Wq,
                                                           const float* __restrict__ Wk,
                                                           const float* __restrict__ Wv,
                                                           unsigned short* __restrict__ dst) {
  __shared__ float t[32][33];
  int n0 = blockIdx.x * 32, k0 = blockIdx.y * 32;   // n0 in [0,3072)
  const float* src; int col0, srcN;
  if (n0 < 2048)      { src = Wq; col0 = n0;        srcN = 2048; }
  else if (n0 < 2560) { src = Wk; col0 = n0 - 2048; srcN = 512; }
  else                { src = Wv; col0 = n0 - 2560; srcN = 512; }
  int x = threadIdx.x, y = threadIdx.y;
  #pragma unroll
  for (int j = 0; j < 32; j += 8)
    t[y + j][x] = src[(size_t)(k0 + y + j) * srcN + col0 + x];
  __syncthreads();
  #pragma unroll
  for (int j = 0; j < 32; j += 8)
    dst[(size_t)(n0 + y + j) * 2048 + k0 + x] = f2bf(t[x][y + j]);
}

// ---------------- bf16 NT GEMM: C[M][N] = A[M][K] * Bt[N][K]^T (fp32 or bf16 out) ----
// m97 structure + XOR-swizzled LDS (swizzle realized via per-lane global address
// permutation in global_load_lds; consumer reads land 2-way/bank = free).
template <typename OutT>
__global__ __launch_bounds__(256) void gemm_nt(const unsigned short* __restrict__ A,
                                               const unsigned short* __restrict__ Bt,
                                               OutT* __restrict__ C,
                                               int M, int N, int K) {
  __shared__ alignas(16) unsigned short As[128 * 32];
  __shared__ alignas(16) unsigned short Bs[128 * 32];
  const int tid = threadIdx.x;
  const int wave = tid >> 6, lane = tid & 63;
  const int g = lane >> 4, c = lane & 15;
  const int m0 = blockIdx.y * 128, n0 = blockIdx.x * 128;
  const int wm = (wave & 1) * 64, wn = (wave >> 1) * 64;

  f32x4 acc[4][4] = {};

  const int ch0 = wave * 2;
  const int p0 = ch0 * 64 + lane, p1 = p0 + 64;
  const int r0 = p0 >> 2, gc0 = ((p0 & 3) ^ ((r0 >> 1) & 3)) * 8;
  const int r1 = p1 >> 2, gc1 = ((p1 & 3) ^ ((r1 >> 1) & 3)) * 8;
  const unsigned short* a0 = A + (size_t)(m0 + r0) * K + gc0;
  const unsigned short* a1 = A + (size_t)(m0 + r1) * K + gc1;
  const unsigned short* b0 = Bt + (size_t)(n0 + r0) * K + gc0;
  const unsigned short* b1 = Bt + (size_t)(n0 + r1) * K + gc1;
  const int fswz = (c >> 1) & 3;   // f(row) for consumer rows (wm,i*16 are mult of 16)

  for (int k0 = 0; k0 < K; k0 += 32) {
    __syncthreads();
    __builtin_amdgcn_global_load_lds(AS1(a0 + k0), AS3(As + ch0 * 512), 16, 0, 0);
    __builtin_amdgcn_global_load_lds(AS1(a1 + k0), AS3(As + ch0 * 512 + 512), 16, 0, 0);
    __builtin_amdgcn_global_load_lds(AS1(b0 + k0), AS3(Bs + ch0 * 512), 16, 0, 0);
    __builtin_amdgcn_global_load_lds(AS1(b1 + k0), AS3(Bs + ch0 * 512 + 512), 16, 0, 0);
    __builtin_amdgcn_s_waitcnt(0);
    __syncthreads();

    bf16x8 af[4], bfr[4];
    #pragma unroll
    for (int i = 0; i < 4; i++)
      af[i] = *(const bf16x8*)(As + (wm + i * 16 + c) * 32 + (g ^ fswz) * 8);
    #pragma unroll
    for (int j = 0; j < 4; j++)
      bfr[j] = *(const bf16x8*)(Bs + (wn + j * 16 + c) * 32 + (g ^ fswz) * 8);
    #pragma unroll
    for (int i = 0; i < 4; i++)
      #pragma unroll
      for (int j = 0; j < 4; j++)
        acc[i][j] = MFMA_BF16(af[i], bfr[j], acc[i][j], 0, 0, 0);
  }

  #pragma unroll
  for (int i = 0; i < 4; i++)
    #pragma unroll
    for (int j = 0; j < 4; j++)
      #pragma unroll
      for (int r = 0; r < 4; r++) {
        size_t idx = (size_t)(m0 + wm + i * 16 + g * 4 + r) * N + n0 + wn + j * 16 + c;
        if constexpr (sizeof(OutT) == 2) C[idx] = f2bf(acc[i][j][r]);
        else                             C[idx] = acc[i][j][r];
      }
}

// ---------------- RMSNorm + RoPE for Q and K heads (bf16 QKV input) ----------------
// SC = log2(e)/sqrt(64) folded into Q here (attention uses exp2 with fixed max 0).
// 4 tasks per wave to amortize wave launch overhead.
__global__ __launch_bounds__(256) void norm_rope(const unsigned short* __restrict__ QKV,
                                                 const float* __restrict__ cosb,
                                                 const float* __restrict__ sinb,
                                                 const float* __restrict__ q_scale,
                                                 const float* __restrict__ k_scale,
                                                 unsigned short* __restrict__ Qn,
                                                 unsigned short* __restrict__ Kn) {
  const int tid = threadIdx.x, w = tid >> 6, d = tid & 63;
  const float qs = q_scale[d], ks = k_scale[d];
  #pragma unroll
  for (int k = 0; k < 4; k++) {
    int task = blockIdx.x * 16 + w * 4 + k;
    const int hid = task % 40;
    const int row = task / 40;            // b*2048 + s
    const int b = row >> 11, s = row & 2047;
    float val, sc;
    if (hid < 32) {
      val = bf2f(QKV[(size_t)row * 3072 + hid * 64 + d]);
      sc = qs;
    } else {
      val = bf2f(QKV[(size_t)row * 3072 + 2048 + (hid - 32) * 64 + d]);
      sc = ks;
    }
    float v2 = val * val;
    #pragma unroll
    for (int off = 32; off; off >>= 1) v2 += __shfl_xor(v2, off);
    float t = val * (1.0f / sqrtf(v2 * (1.0f / 64.0f) + 1e-6f)) * sc;
    float partner = __shfl_xor(t, 32);
    float rot = (d < 32) ? -partner : partner;
    float o = t * cosb[s * 64 + d] + rot * sinb[s * 64 + d];
    if (hid < 32) o *= 0.18033688011112042f;   // fold softmax scale into Q
    unsigned short ob = f2bf(o);
    if (hid < 32) Qn[((size_t)(b * 32 + hid) * 2048 + s) * 64 + d] = ob;
    else          Kn[((size_t)(b * 8 + (hid - 32)) * 2048 + s) * 64 + d] = ob;
  }
}

// ---------------- V transpose: bf16 QKV V-cols -> Vt bf16 [b][kv][D][S] ----------------
__global__ __launch_bounds__(256) void v_transpose(const unsigned short* __restrict__ QKV,
                                                   unsigned short* __restrict__ Vt) {
  __shared__ unsigned int t[64][65];
  int bid = blockIdx.x;
  const int st = bid & 31, kv = (bid >> 5) & 7, b = bid >> 8;
  const int tid = threadIdx.x, lane = tid & 63, quad = tid >> 6;
  #pragma unroll
  for (int p = 0; p < 16; p++) {
    int sl = p * 4 + quad;
    t[sl][lane] = QKV[(size_t)(b * 2048 + st * 64 + sl) * 3072 + 2560 + kv * 64 + lane];
  }
  __syncthreads();
  size_t base = (size_t)(b * 8 + kv) * 64 * 2048;
  #pragma unroll
  for (int p = 0; p < 16; p++) {
    int dd = p * 4 + quad;
    Vt[base + (size_t)dd * 2048 + st * 64 + lane] = (unsigned short)t[lane][dd];
  }
}

// ---------------- causal flash attention v9 ----------------
// v8 post-mortem: launch_bounds(256,4) with ~150 live regs -> ~20+ spilled in
// the hot loop (WRITE_SIZE 16->435 MB, 2x slower). v9 makes the state GENUINELY
// fit 128: KV tile 64 -> 32 (ak[2][2]=16 regs, was 32), single V tile reloaded
// in place (av[4]=16, was 32), lv collapsed to 2 scalars (tree-sum, same VALU
// count). MFMA + softmax work per kv unchanged; only loop overhead doubles.
// Hand count of peak live state ~115 regs. Numeric path identical to verified
// v6/v8 (v_perm pack, VALU lv, shfl butterfly). Load order V(i)..K(i+1)..V(i+1)
// keeps compiler vmcnt counted (never drains prefetches).
__global__ __launch_bounds__(256, 4) void attn_kernel(const unsigned short* __restrict__ Qn,
                                                      const unsigned short* __restrict__ Kn,
                                                      const unsigned short* __restrict__ Vt,
                                                      unsigned short* __restrict__ Outv) {
  __shared__ alignas(16) char smem[4 * 4352];

  const int tid = threadIdx.x, w = tid >> 6, lane = tid & 63;
  const int g = lane >> 4, c = lane & 15;
  const int bid = blockIdx.x;                      // [0, 1024)
  const int qt = 63 - (bid >> 4);                  // longest blocks first
  const int rem = bid & 15;
  const int hg = rem & 7, b = rem >> 3;
  const int h = hg * 4 + w;
  const int kvh = hg;
  const int Q0 = qt * 32;
  const unsigned short* Qp = Qn + ((size_t)(b * NHEADS + h) * S_LEN + Q0) * HDIM;
  const unsigned short* Kp = Kn + (size_t)(b * NKV + kvh) * S_LEN * HDIM;
  const unsigned short* Vp = Vt + (size_t)(b * NKV + kvh) * HDIM * S_LEN;  // [d][s]
  const int ntiles = qt + 1;                       // 32-kv tiles
  char* PwB = smem + w * 4352;   // this wave's P buffer (32 rows x 128 B, swizzled)

  // Q as B-operand: B[k=d][n=q], n = c, k = g*8+j (+t*32)
  bf16x8 bq[2][2];
  #pragma unroll
  for (int iq = 0; iq < 2; iq++)
    #pragma unroll
    for (int t = 0; t < 2; t++)
      bq[iq][t] = *(const bf16x8*)(Qp + (iq * 16 + c) * HDIM + t * 32 + g * 8);

  f32x4 OT[4][2] = {};          // O^T tiles: [dt][iq], row=d, col=q
  float lv[2] = {0.f, 0.f};     // per-lane l partials (scalar)

  const unsigned short* Kl = Kp + c * HDIM + g * 8;      // lane-invariant bases
  const unsigned short* Vl = Vp + c * S_LEN + g * 8;

  bf16x8 ak[2][2];              // current 32-kv K tile (A-operand: A[m=kv][k=d])
  #pragma unroll
  for (int jt = 0; jt < 2; jt++)
    #pragma unroll
    for (int t = 0; t < 2; t++)
      ak[jt][t] = *(const bf16x8*)(Kl + jt * 16 * HDIM + t * 32);

  bf16x8 av[4];                 // current 32-kv V tile (A-operand: A[m=d][k=kv])
  #pragma unroll
  for (int dt = 0; dt < 4; dt++)
    av[dt] = *(const bf16x8*)(Vl + dt * 16 * S_LEN);

  for (int ti = 0; ti < ntiles; ti++) {
    const int kv0 = ti * 32;

    // S^T = K · Q^T : rows kv (32), cols q (32)
    f32x4 Sx[2][2] = {};
    #pragma unroll
    for (int t = 0; t < 2; t++)
      #pragma unroll
      for (int jt = 0; jt < 2; jt++)
        #pragma unroll
        for (int iq = 0; iq < 2; iq++)
          Sx[jt][iq] = MFMA_BF16(ak[jt][t], bq[iq][t], Sx[jt][iq], 0, 0, 0);

    // in-place prefetch of next K tile (ak dead once QK MFMAs issue)
    if (ti + 1 < ntiles) {
      #pragma unroll
      for (int jt = 0; jt < 2; jt++)
        #pragma unroll
        for (int t = 0; t < 2; t++)
          ak[jt][t] = *(const bf16x8*)(Kl + (kv0 + 32 + jt * 16) * HDIM + t * 32);
    }

    if (ti == ntiles - 1) {     // only the final tile crosses the diagonal
      #pragma unroll
      for (int jt = 0; jt < 2; jt++)
        #pragma unroll
        for (int iq = 0; iq < 2; iq++)
          #pragma unroll
          for (int r = 0; r < 4; r++) {
            int kv = kv0 + jt * 16 + g * 4 + r;
            int q  = Q0 + iq * 16 + c;
            if (kv > q) Sx[jt][iq][r] = -1e30f;
          }
    }

    // fixed-max softmax: p = exp2(s); accumulate l; pack P -> LDS (swizzled)
    #pragma unroll
    for (int jt = 0; jt < 2; jt++)
      #pragma unroll
      for (int iq = 0; iq < 2; iq++) {
        f32x4 p;
        #pragma unroll
        for (int r = 0; r < 4; r++) p[r] = EXP2F(Sx[jt][iq][r]);
        lv[iq] += (p[0] + p[1]) + (p[2] + p[3]);
        uint32_t u0 = __float_as_uint(p[0]) + 0x8000u;
        uint32_t u1 = __float_as_uint(p[1]) + 0x8000u;
        uint32_t u2 = __float_as_uint(p[2]) + 0x8000u;
        uint32_t u3 = __float_as_uint(p[3]) + 0x8000u;
        uint32_t lo = __builtin_amdgcn_perm(u1, u0, 0x07060302u);
        uint32_t hi = __builtin_amdgcn_perm(u3, u2, 0x07060302u);
        int row = iq * 16 + c;                 // local q
        int bytecol = jt * 32 + g * 8;         // kv-contiguous bytes [0,64)
        uint32_t off = row * 128 + (((bytecol >> 4) ^ (row & 7)) << 4) + (bytecol & 15);
        *(uint2*)(PwB + off) = make_uint2(lo, hi);
      }

    __builtin_amdgcn_s_waitcnt(0xC07F);        // lgkmcnt(0) only — keep VMEM in flight

    // P as B-operand: B[k=kv][n=q]; one swizzled b128 per iq (wave-private)
    bf16x8 bp[2];
    #pragma unroll
    for (int iq = 0; iq < 2; iq++) {
      int row = iq * 16 + c;
      bp[iq] = *(const bf16x8*)(PwB + row * 128 + ((g ^ (row & 7)) << 4));
    }
    #pragma unroll
    for (int dt = 0; dt < 4; dt++)
      #pragma unroll
      for (int iq = 0; iq < 2; iq++)
        OT[dt][iq] = MFMA_BF16(av[dt], bp[iq], OT[dt][iq], 0, 0, 0);

    // in-place prefetch of next V tile (av dead once PV MFMAs issue)
    if (ti + 1 < ntiles) {
      #pragma unroll
      for (int dt = 0; dt < 4; dt++)
        av[dt] = *(const bf16x8*)(Vl + dt * 16 * S_LEN + kv0 + 32);
    }
  }

  // l: per-lane partial covers its 4 kv rows; butterfly over g (16, 32)
  float inv[2];
  #pragma unroll
  for (int iq = 0; iq < 2; iq++) {
    float s = lv[iq];
    s += __shfl_xor(s, 16);
    s += __shfl_xor(s, 32);
    inv[iq] = 1.0f / s;
  }

  // write O: lane holds d = dt*16+g*4+{0..3}, q = Q0+iq*16+c -> 8B stores
  #pragma unroll
  for (int iq = 0; iq < 2; iq++) {
    const int q = Q0 + iq * 16 + c;
    unsigned short* orow = Outv + (size_t)(b * S_LEN + q) * (NHEADS * HDIM) + h * HDIM;
    #pragma unroll
    for (int dt = 0; dt < 4; dt++) {
      uint32_t u0 = __float_as_uint(OT[dt][iq][0] * inv[iq]) + 0x8000u;
      uint32_t u1 = __float_as_uint(OT[dt][iq][1] * inv[iq]) + 0x8000u;
      uint32_t u2 = __float_as_uint(OT[dt][iq][2] * inv[iq]) + 0x8000u;
      uint32_t u3 = __float_as_uint(OT[dt][iq][3] * inv[iq]) + 0x8000u;
      uint32_t lo = __builtin_amdgcn_perm(u1, u0, 0x07060302u);
      uint32_t hi = __builtin_amdgcn_perm(u3, u2, 0x07060302u);
      *(uint2*)(orow + dt * 16 + g * 4) = make_uint2(lo, hi);
    }
  }
}

extern "C" void kernel_launch(void* const* d_in, const int* in_sizes, int n_in,
                              void* d_out, int out_size, void* d_ws, size_t ws_size,
                              hipStream_t stream) {
  const float* x       = (const float*)d_in[0];
  // d_in[1] = mask (causal, implemented analytically)
  const float* cosb    = (const float*)d_in[2];
  const float* sinb    = (const float*)d_in[3];
  const float* Wq      = (const float*)d_in[4];
  const float* Wk      = (const float*)d_in[5];
  const float* Wv      = (const float*)d_in[6];
  const float* Wo      = (const float*)d_in[7];
  const float* q_scale = (const float*)d_in[8];
  const float* k_scale = (const float*)d_in[9];

  char* ws = (char*)d_ws;
  unsigned short* xb   = (unsigned short*)(ws);                       // 16 MiB: x bf16 [4096][2048]
  unsigned short* wcat = (unsigned short*)(ws + (16ull << 20));       // 12 MiB: Wt [3072][2048]
  unsigned short* wo_t = (unsigned short*)(ws + (28ull << 20));       //  8 MiB: Wo_t [2048][2048]
  unsigned short* qkv  = (unsigned short*)(ws + (36ull << 20));       // 24 MiB: QKV bf16 [4096][3072]
  unsigned short* qn   = (unsigned short*)(ws + (84ull << 20));       // 16 MiB: Q bf16 [b][h][s][d]
  unsigned short* kn   = (unsigned short*)(ws + (100ull << 20));      //  4 MiB: K bf16 [b][kv][s][d]
  unsigned short* vt   = (unsigned short*)(ws + (104ull << 20));      //  4 MiB: V^T bf16 [b][kv][d][s]
  unsigned short* vec  = (unsigned short*)(ws + (36ull << 20));       // alias qkv (dead after v_transpose)

  cast_x_kernel<<<8192, 256, 0, stream>>>(x, xb, 2097152);
  dim3 tb(32, 8);
  transpose_cast_wqkv<<<dim3(96, 64), tb, 0, stream>>>(Wq, Wk, Wv, wcat);
  transpose_cast<<<dim3(64, 64), tb, 0, stream>>>(Wo, wo_t, 2048, 2048);

  gemm_nt<unsigned short><<<dim3(24, 32), 256, 0, stream>>>(xb, wcat, qkv, 4096, 3072, 2048);
  norm_rope<<<10240, 256, 0, stream>>>(qkv, cosb, sinb, q_scale, k_scale, qn, kn);
  v_transpose<<<512, 256, 0, stream>>>(qkv, vt);
  attn_kernel<<<1024, 256, 0, stream>>>(qn, kn, vt, vec);
  gemm_nt<float><<<dim3(16, 32), 256, 0, stream>>>(vec, wo_t, (float*)d_out, 4096, 2048, 2048);
}

// Round 5
// 340.045 us; speedup vs baseline: 1.6477x; 1.2709x over previous
//
#include <hip/hip_runtime.h>
#include <hip/hip_bf16.h>
#include <stdint.h>

#define S_LEN   2048
#define DIN     2048
#define NHEADS  32
#define HDIM    64
#define NKV     8

typedef __bf16 bf16x8 __attribute__((ext_vector_type(8)));
typedef float  f32x4  __attribute__((ext_vector_type(4)));

#define AS1(p) ((__attribute__((address_space(1))) void*)(void*)(p))
#define AS3(p) ((__attribute__((address_space(3))) void*)(p))
#define MFMA_BF16 __builtin_amdgcn_mfma_f32_16x16x32_bf16

#if __has_builtin(__builtin_amdgcn_exp2f)
#define EXP2F(x) __builtin_amdgcn_exp2f(x)
#else
#define EXP2F(x) exp2f(x)
#endif

static __device__ __forceinline__ unsigned short f2bf(float f) {
  unsigned int x = __float_as_uint(f);
  return (unsigned short)((x + 0x7fffu + ((x >> 16) & 1u)) >> 16);
}
static __device__ __forceinline__ float bf2f(unsigned short u) {
  return __uint_as_float((unsigned int)u << 16);
}

// ---------------- cast x (fp32 -> bf16), vectorized ----------------
__global__ __launch_bounds__(256) void cast_x_kernel(const float* __restrict__ x,
                                                     unsigned short* __restrict__ xb, int n4) {
  int i = blockIdx.x * 256 + threadIdx.x;
  if (i >= n4) return;
  float4 f = ((const float4*)x)[i];
  ushort4 o = make_ushort4(f2bf(f.x), f2bf(f.y), f2bf(f.z), f2bf(f.w));
  ((ushort4*)xb)[i] = o;
}

// ---------------- transpose + cast: src fp32 [K][N] -> dst bf16 [N][K] ----------------
__global__ __launch_bounds__(256) void transpose_cast(const float* __restrict__ src,
                                                      unsigned short* __restrict__ dst,
                                                      int K, int N) {
  __shared__ float t[32][33];
  int n0 = blockIdx.x * 32, k0 = blockIdx.y * 32;
  int x = threadIdx.x, y = threadIdx.y;
  #pragma unroll
  for (int j = 0; j < 32; j += 8)
    t[y + j][x] = src[(size_t)(k0 + y + j) * N + n0 + x];
  __syncthreads();
  #pragma unroll
  for (int j = 0; j < 32; j += 8)
    dst[(size_t)(n0 + y + j) * K + k0 + x] = f2bf(t[x][y + j]);
}

// ---------------- fused W transpose: [Wq|Wk|Wv] -> wcat bf16 [3072][2048] ----------------
__global__ __launch_bounds__(256) void transpose_cast_wqkv(const float* __restrict__ Wq,
                                                           const float* __restrict__ Wk,
                                                           const float* __restrict__ Wv,
                                                           unsigned short* __restrict__ dst) {
  __shared__ float t[32][33];
  int n0 = blockIdx.x * 32, k0 = blockIdx.y * 32;   // n0 in [0,3072)
  const float* src; int col0, srcN;
  if (n0 < 2048)      { src = Wq; col0 = n0;        srcN = 2048; }
  else if (n0 < 2560) { src = Wk; col0 = n0 - 2048; srcN = 512; }
  else                { src = Wv; col0 = n0 - 2560; srcN = 512; }
  int x = threadIdx.x, y = threadIdx.y;
  #pragma unroll
  for (int j = 0; j < 32; j += 8)
    t[y + j][x] = src[(size_t)(k0 + y + j) * srcN + col0 + x];
  __syncthreads();
  #pragma unroll
  for (int j = 0; j < 32; j += 8)
    dst[(size_t)(n0 + y + j) * 2048 + k0 + x] = f2bf(t[x][y + j]);
}

// ---------------- bf16 NT GEMM: C[M][N] = A[M][K] * Bt[N][K]^T (fp32 or bf16 out) ----
template <typename OutT>
__global__ __launch_bounds__(256) void gemm_nt(const unsigned short* __restrict__ A,
                                               const unsigned short* __restrict__ Bt,
                                               OutT* __restrict__ C,
                                               int M, int N, int K) {
  __shared__ alignas(16) unsigned short As[128 * 32];
  __shared__ alignas(16) unsigned short Bs[128 * 32];
  const int tid = threadIdx.x;
  const int wave = tid >> 6, lane = tid & 63;
  const int g = lane >> 4, c = lane & 15;
  const int m0 = blockIdx.y * 128, n0 = blockIdx.x * 128;
  const int wm = (wave & 1) * 64, wn = (wave >> 1) * 64;

  f32x4 acc[4][4] = {};

  const int ch0 = wave * 2;
  const int p0 = ch0 * 64 + lane, p1 = p0 + 64;
  const int r0 = p0 >> 2, gc0 = ((p0 & 3) ^ ((r0 >> 1) & 3)) * 8;
  const int r1 = p1 >> 2, gc1 = ((p1 & 3) ^ ((r1 >> 1) & 3)) * 8;
  const unsigned short* a0 = A + (size_t)(m0 + r0) * K + gc0;
  const unsigned short* a1 = A + (size_t)(m0 + r1) * K + gc1;
  const unsigned short* b0 = Bt + (size_t)(n0 + r0) * K + gc0;
  const unsigned short* b1 = Bt + (size_t)(n0 + r1) * K + gc1;
  const int fswz = (c >> 1) & 3;   // f(row) for consumer rows (wm,i*16 are mult of 16)

  for (int k0 = 0; k0 < K; k0 += 32) {
    __syncthreads();
    __builtin_amdgcn_global_load_lds(AS1(a0 + k0), AS3(As + ch0 * 512), 16, 0, 0);
    __builtin_amdgcn_global_load_lds(AS1(a1 + k0), AS3(As + ch0 * 512 + 512), 16, 0, 0);
    __builtin_amdgcn_global_load_lds(AS1(b0 + k0), AS3(Bs + ch0 * 512), 16, 0, 0);
    __builtin_amdgcn_global_load_lds(AS1(b1 + k0), AS3(Bs + ch0 * 512 + 512), 16, 0, 0);
    __builtin_amdgcn_s_waitcnt(0);
    __syncthreads();

    bf16x8 af[4], bfr[4];
    #pragma unroll
    for (int i = 0; i < 4; i++)
      af[i] = *(const bf16x8*)(As + (wm + i * 16 + c) * 32 + (g ^ fswz) * 8);
    #pragma unroll
    for (int j = 0; j < 4; j++)
      bfr[j] = *(const bf16x8*)(Bs + (wn + j * 16 + c) * 32 + (g ^ fswz) * 8);
    #pragma unroll
    for (int i = 0; i < 4; i++)
      #pragma unroll
      for (int j = 0; j < 4; j++)
        acc[i][j] = MFMA_BF16(af[i], bfr[j], acc[i][j], 0, 0, 0);
  }

  #pragma unroll
  for (int i = 0; i < 4; i++)
    #pragma unroll
    for (int j = 0; j < 4; j++)
      #pragma unroll
      for (int r = 0; r < 4; r++) {
        size_t idx = (size_t)(m0 + wm + i * 16 + g * 4 + r) * N + n0 + wn + j * 16 + c;
        if constexpr (sizeof(OutT) == 2) C[idx] = f2bf(acc[i][j][r]);
        else                             C[idx] = acc[i][j][r];
      }
}

// ---------------- RMSNorm + RoPE for Q and K heads (bf16 QKV input) ----------------
__global__ __launch_bounds__(256) void norm_rope(const unsigned short* __restrict__ QKV,
                                                 const float* __restrict__ cosb,
                                                 const float* __restrict__ sinb,
                                                 const float* __restrict__ q_scale,
                                                 const float* __restrict__ k_scale,
                                                 unsigned short* __restrict__ Qn,
                                                 unsigned short* __restrict__ Kn) {
  const int tid = threadIdx.x, w = tid >> 6, d = tid & 63;
  const float qs = q_scale[d], ks = k_scale[d];
  #pragma unroll
  for (int k = 0; k < 4; k++) {
    int task = blockIdx.x * 16 + w * 4 + k;
    const int hid = task % 40;
    const int row = task / 40;            // b*2048 + s
    const int b = row >> 11, s = row & 2047;
    float val, sc;
    if (hid < 32) {
      val = bf2f(QKV[(size_t)row * 3072 + hid * 64 + d]);
      sc = qs;
    } else {
      val = bf2f(QKV[(size_t)row * 3072 + 2048 + (hid - 32) * 64 + d]);
      sc = ks;
    }
    float v2 = val * val;
    #pragma unroll
    for (int off = 32; off; off >>= 1) v2 += __shfl_xor(v2, off);
    float t = val * (1.0f / sqrtf(v2 * (1.0f / 64.0f) + 1e-6f)) * sc;
    float partner = __shfl_xor(t, 32);
    float rot = (d < 32) ? -partner : partner;
    float o = t * cosb[s * 64 + d] + rot * sinb[s * 64 + d];
    if (hid < 32) o *= 0.18033688011112042f;   // fold softmax scale into Q
    unsigned short ob = f2bf(o);
    if (hid < 32) Qn[((size_t)(b * 32 + hid) * 2048 + s) * 64 + d] = ob;
    else          Kn[((size_t)(b * 8 + (hid - 32)) * 2048 + s) * 64 + d] = ob;
  }
}

// ---------------- V transpose: bf16 QKV V-cols -> Vt bf16 [b][kv][D][S] ----------------
__global__ __launch_bounds__(256) void v_transpose(const unsigned short* __restrict__ QKV,
                                                   unsigned short* __restrict__ Vt) {
  __shared__ unsigned int t[64][65];
  int bid = blockIdx.x;
  const int st = bid & 31, kv = (bid >> 5) & 7, b = bid >> 8;
  const int tid = threadIdx.x, lane = tid & 63, quad = tid >> 6;
  #pragma unroll
  for (int p = 0; p < 16; p++) {
    int sl = p * 4 + quad;
    t[sl][lane] = QKV[(size_t)(b * 2048 + st * 64 + sl) * 3072 + 2560 + kv * 64 + lane];
  }
  __syncthreads();
  size_t base = (size_t)(b * 8 + kv) * 64 * 2048;
  #pragma unroll
  for (int p = 0; p < 16; p++) {
    int dd = p * 4 + quad;
    Vt[base + (size_t)dd * 2048 + st * 64 + lane] = (unsigned short)t[lane][dd];
  }
}

// ---------------- causal flash attention v10 ----------------
// v9 post-mortem: occupancy was NOT the constraint (34% occ, 8.9% MfmaUtil,
// SLOWER). Waves stall ~90% of each tile on K/V loads at L2/L3 latency; all
// 4 waves of a block load the SAME K/V head redundantly. v10: cooperative
// double-buffered LDS staging of the shared 64-kv K (8KB) + V^T (8KB) tiles
// via global_load_lds(16B), stage(i+1) issued at start of tile i (full-tile
// prefetch distance), one barrier per tile. Fragment reads hit LDS (~120cy)
// with XOR swizzle (slot ^= row&7) realized by pre-swizzling the per-lane
// GLOBAL source (linear LDS dest, rule 21); reads land as same-address
// broadcast x4 + 2 rows/bank-group = free. Numerics bit-identical to v6/v9.
__global__ __launch_bounds__(256, 3) void attn_kernel(const unsigned short* __restrict__ Qn,
                                                      const unsigned short* __restrict__ Kn,
                                                      const unsigned short* __restrict__ Vt,
                                                      unsigned short* __restrict__ Outv) {
  __shared__ alignas(16) unsigned short Ksh[2][4096];   // [buf][64 rows x 64 d]
  __shared__ alignas(16) unsigned short Vsh[2][4096];   // [buf][64 rows(d) x 64 kv]
  __shared__ alignas(16) char Psh[4][4352];             // per-wave P buffers

  const int tid = threadIdx.x, w = tid >> 6, lane = tid & 63;
  const int g = lane >> 4, c = lane & 15;
  const int cs = c & 7;
  const int rl = (lane >> 3) & 7;      // staging: row within 1KB chunk
  const int sl = lane & 7;             // staging: 16B slot within row
  const int swz = (sl ^ rl) << 3;      // pre-swizzled source column (elements)
  const int bid = blockIdx.x;                      // [0, 1024)
  const int qt = 63 - (bid >> 4);                  // longest blocks first
  const int rem = bid & 15;
  const int hg = rem & 7, b = rem >> 3;
  const int h = hg * 4 + w;
  const int Q0 = qt * 32;
  const unsigned short* Qp = Qn + ((size_t)(b * NHEADS + h) * S_LEN + Q0) * HDIM;
  const unsigned short* Kp = Kn + (size_t)(b * NKV + hg) * S_LEN * HDIM;
  const unsigned short* Vp = Vt + (size_t)(b * NKV + hg) * HDIM * S_LEN;  // [d][s]
  const int ntiles = (qt >> 1) + 1;
  char* PwB = Psh[w];                  // 32 rows x 128 B, swizzled

  // Q as B-operand: B[k=d][n=q], n = c, k = g*8+j (+t*32)
  bf16x8 bq[2][2];
  #pragma unroll
  for (int iq = 0; iq < 2; iq++)
    #pragma unroll
    for (int t = 0; t < 2; t++)
      bq[iq][t] = *(const bf16x8*)(Qp + (iq * 16 + c) * HDIM + t * 32 + g * 8);

  f32x4 OT[4][2] = {};          // O^T tiles: [dt][iq], row=d, col=q
  float lv[2] = {0.f, 0.f};     // per-lane l partials

  const int wr0 = w * 16;       // this wave's 16 staging rows

  // stage K rows [kv0+wr0, +16) and V^T rows [wr0, +16) of the kv window
  auto STAGE = [&](int kv0s, int bi) {
    #pragma unroll
    for (int q = 0; q < 2; q++) {
      const int rr = wr0 + q * 8;
      __builtin_amdgcn_global_load_lds(AS1(Kp + (size_t)(kv0s + rr + rl) * 64 + swz),
                                       AS3(&Ksh[bi][rr * 64]), 16, 0, 0);
      __builtin_amdgcn_global_load_lds(AS1(Vp + (size_t)(rr + rl) * 2048 + kv0s + swz),
                                       AS3(&Vsh[bi][rr * 64]), 16, 0, 0);
    }
  };

  STAGE(0, 0);
  __syncthreads();

  for (int ti = 0; ti < ntiles; ti++) {
    const int kv0 = ti * 64;
    const int cur = ti & 1;
    if (ti + 1 < ntiles) STAGE(kv0 + 64, cur ^ 1);

    const unsigned short* Kb = Ksh[cur];
    const unsigned short* Vb = Vsh[cur];

    // QK + softmax in two jt-pairs (Sx live = 16 regs)
    #pragma unroll
    for (int jb = 0; jb < 2; jb++) {
      bf16x8 akx[2][2];
      #pragma unroll
      for (int jt = 0; jt < 2; jt++)
        #pragma unroll
        for (int t = 0; t < 2; t++)
          akx[jt][t] = *(const bf16x8*)(Kb + ((jb * 2 + jt) * 16 + c) * 64 +
                                        (((t * 4 + g) ^ cs) << 3));
      f32x4 Sx[2][2] = {};
      #pragma unroll
      for (int t = 0; t < 2; t++)
        #pragma unroll
        for (int jt = 0; jt < 2; jt++)
          #pragma unroll
          for (int iq = 0; iq < 2; iq++)
            Sx[jt][iq] = MFMA_BF16(akx[jt][t], bq[iq][t], Sx[jt][iq], 0, 0, 0);

      if (ti == ntiles - 1) {   // only the final tile crosses the diagonal
        #pragma unroll
        for (int jt = 0; jt < 2; jt++)
          #pragma unroll
          for (int iq = 0; iq < 2; iq++)
            #pragma unroll
            for (int r = 0; r < 4; r++) {
              int kv = kv0 + (jb * 2 + jt) * 16 + g * 4 + r;
              int q  = Q0 + iq * 16 + c;
              if (kv > q) Sx[jt][iq][r] = -1e30f;
            }
      }

      // fixed-max softmax: p = exp2(s); accumulate l; pack P -> LDS (swizzled)
      #pragma unroll
      for (int jt = 0; jt < 2; jt++)
        #pragma unroll
        for (int iq = 0; iq < 2; iq++) {
          f32x4 p;
          #pragma unroll
          for (int r = 0; r < 4; r++) p[r] = EXP2F(Sx[jt][iq][r]);
          lv[iq] += (p[0] + p[1]) + (p[2] + p[3]);
          uint32_t u0 = __float_as_uint(p[0]) + 0x8000u;
          uint32_t u1 = __float_as_uint(p[1]) + 0x8000u;
          uint32_t u2 = __float_as_uint(p[2]) + 0x8000u;
          uint32_t u3 = __float_as_uint(p[3]) + 0x8000u;
          uint32_t lo = __builtin_amdgcn_perm(u1, u0, 0x07060302u);
          uint32_t hi = __builtin_amdgcn_perm(u3, u2, 0x07060302u);
          int row = iq * 16 + c;                       // local q
          int bytecol = (jb * 2 + jt) * 32 + g * 8;    // kv-contiguous bytes
          uint32_t off = row * 128 + (((bytecol >> 4) ^ (row & 7)) << 4) + (bytecol & 15);
          *(uint2*)(PwB + off) = make_uint2(lo, hi);
        }
    }

    __builtin_amdgcn_s_waitcnt(0xC07F);        // lgkmcnt(0): P writes visible

    // PV per t-half: V from LDS, P as B-operand B[k=kv][n=q]
    #pragma unroll
    for (int t = 0; t < 2; t++) {
      bf16x8 avt[4];
      #pragma unroll
      for (int dt = 0; dt < 4; dt++)
        avt[dt] = *(const bf16x8*)(Vb + (dt * 16 + c) * 64 + (((t * 4 + g) ^ cs) << 3));
      bf16x8 bpt[2];
      #pragma unroll
      for (int iq = 0; iq < 2; iq++) {
        int row = iq * 16 + c;
        int bytecol = t * 64 + g * 16;
        uint32_t off = row * 128 + (((bytecol >> 4) ^ (row & 7)) << 4);
        bpt[iq] = *(const bf16x8*)(PwB + off);
      }
      #pragma unroll
      for (int dt = 0; dt < 4; dt++)
        #pragma unroll
        for (int iq = 0; iq < 2; iq++)
          OT[dt][iq] = MFMA_BF16(avt[dt], bpt[iq], OT[dt][iq], 0, 0, 0);
    }

    if (ti + 1 < ntiles) __syncthreads();      // stage(i+1) drained + all reads done
  }

  // l: per-lane partial covers kv rows {jt*16+g*4+r}; butterfly over g
  float inv[2];
  #pragma unroll
  for (int iq = 0; iq < 2; iq++) {
    float s = lv[iq];
    s += __shfl_xor(s, 16);
    s += __shfl_xor(s, 32);
    inv[iq] = 1.0f / s;
  }

  // write O: lane holds d = dt*16+g*4+{0..3}, q = Q0+iq*16+c -> 8B stores
  #pragma unroll
  for (int iq = 0; iq < 2; iq++) {
    const int q = Q0 + iq * 16 + c;
    unsigned short* orow = Outv + (size_t)(b * S_LEN + q) * (NHEADS * HDIM) + h * HDIM;
    #pragma unroll
    for (int dt = 0; dt < 4; dt++) {
      uint32_t u0 = __float_as_uint(OT[dt][iq][0] * inv[iq]) + 0x8000u;
      uint32_t u1 = __float_as_uint(OT[dt][iq][1] * inv[iq]) + 0x8000u;
      uint32_t u2 = __float_as_uint(OT[dt][iq][2] * inv[iq]) + 0x8000u;
      uint32_t u3 = __float_as_uint(OT[dt][iq][3] * inv[iq]) + 0x8000u;
      uint32_t lo = __builtin_amdgcn_perm(u1, u0, 0x07060302u);
      uint32_t hi = __builtin_amdgcn_perm(u3, u2, 0x07060302u);
      *(uint2*)(orow + dt * 16 + g * 4) = make_uint2(lo, hi);
    }
  }
}

extern "C" void kernel_launch(void* const* d_in, const int* in_sizes, int n_in,
                              void* d_out, int out_size, void* d_ws, size_t ws_size,
                              hipStream_t stream) {
  const float* x       = (const float*)d_in[0];
  // d_in[1] = mask (causal, implemented analytically)
  const float* cosb    = (const float*)d_in[2];
  const float* sinb    = (const float*)d_in[3];
  const float* Wq      = (const float*)d_in[4];
  const float* Wk      = (const float*)d_in[5];
  const float* Wv      = (const float*)d_in[6];
  const float* Wo      = (const float*)d_in[7];
  const float* q_scale = (const float*)d_in[8];
  const float* k_scale = (const float*)d_in[9];

  char* ws = (char*)d_ws;
  unsigned short* xb   = (unsigned short*)(ws);                       // 16 MiB: x bf16 [4096][2048]
  unsigned short* wcat = (unsigned short*)(ws + (16ull << 20));       // 12 MiB: Wt [3072][2048]
  unsigned short* wo_t = (unsigned short*)(ws + (28ull << 20));       //  8 MiB: Wo_t [2048][2048]
  unsigned short* qkv  = (unsigned short*)(ws + (36ull << 20));       // 24 MiB: QKV bf16 [4096][3072]
  unsigned short* qn   = (unsigned short*)(ws + (84ull << 20));       // 16 MiB: Q bf16 [b][h][s][d]
  unsigned short* kn   = (unsigned short*)(ws + (100ull << 20));      //  4 MiB: K bf16 [b][kv][s][d]
  unsigned short* vt   = (unsigned short*)(ws + (104ull << 20));      //  4 MiB: V^T bf16 [b][kv][d][s]
  unsigned short* vec  = (unsigned short*)(ws + (36ull << 20));       // alias qkv (dead after v_transpose)

  cast_x_kernel<<<8192, 256, 0, stream>>>(x, xb, 2097152);
  dim3 tb(32, 8);
  transpose_cast_wqkv<<<dim3(96, 64), tb, 0, stream>>>(Wq, Wk, Wv, wcat);
  transpose_cast<<<dim3(64, 64), tb, 0, stream>>>(Wo, wo_t, 2048, 2048);

  gemm_nt<unsigned short><<<dim3(24, 32), 256, 0, stream>>>(xb, wcat, qkv, 4096, 3072, 2048);
  norm_rope<<<10240, 256, 0, stream>>>(qkv, cosb, sinb, q_scale, k_scale, qn, kn);
  v_transpose<<<512, 256, 0, stream>>>(qkv, vt);
  attn_kernel<<<1024, 256, 0, stream>>>(qn, kn, vt, vec);
  gemm_nt<float><<<dim3(16, 32), 256, 0, stream>>>(vec, wo_t, (float*)d_out, 4096, 2048, 2048);
}